// Round 1
// 2648.649 us; speedup vs baseline: 1.2357x; 1.2357x over previous
//
#include <hip/hip_runtime.h>

#define NN 50000
#define TT 64
#define FF 64
#define EE 800000

typedef __attribute__((ext_vector_type(4))) float f32x4;
typedef __attribute__((ext_vector_type(8))) short bf16x8;

__device__ __forceinline__ unsigned short f2bf(float x) {
  unsigned int u = __float_as_uint(x);
  u = (u + 0x7FFFu + ((u >> 16) & 1u)) >> 16;  // RNE
  return (unsigned short)u;
}
__device__ __forceinline__ float bf2f(unsigned short h) {
  return __uint_as_float(((unsigned int)h) << 16);
}

// ---- CSR build --------------------------------------------------------------

__global__ void k_count(const int* __restrict__ dst, int* __restrict__ cnt) {
  int e = blockIdx.x * 256 + threadIdx.x;
  if (e < EE) atomicAdd(&cnt[dst[e]], 1);
}

__global__ void k_dis(const int* __restrict__ cnt, float* __restrict__ dis) {
  int n = blockIdx.x * 256 + threadIdx.x;
  if (n < NN) dis[n] = rsqrtf((float)(cnt[n] + 1));
}

// exclusive scan of (cnt[n]+1) -> off[0..NN], single block of 1024 threads
__global__ void k_scan(const int* __restrict__ cnt, int* __restrict__ off) {
  __shared__ int s[1024];
  __shared__ int carry;
  int tid = threadIdx.x;
  if (tid == 0) carry = 0;
  __syncthreads();
  for (int base = 0; base < NN; base += 1024) {
    int i = base + tid;
    int v = (i < NN) ? (cnt[i] + 1) : 0;
    s[tid] = v;
    __syncthreads();
    for (int d = 1; d < 1024; d <<= 1) {
      int x = (tid >= d) ? s[tid - d] : 0;
      __syncthreads();
      s[tid] += x;
      __syncthreads();
    }
    if (i < NN) off[i] = carry + s[tid] - v;
    __syncthreads();
    if (tid == 0) carry += s[1023];
    __syncthreads();
  }
  if (tid == 0) off[NN] = carry;
}

__global__ void k_self(const int* __restrict__ off, const float* __restrict__ dis,
                       int2* __restrict__ edges, int* __restrict__ fill) {
  int n = blockIdx.x * 256 + threadIdx.x;
  if (n < NN) {
    float d = dis[n];
    edges[off[n]] = make_int2(n, __float_as_int(d * d));  // self weight = 1/deg
    fill[n] = 1;
  }
}

__global__ void k_fill(const int* __restrict__ src, const int* __restrict__ dst,
                       const int* __restrict__ off, const float* __restrict__ dis,
                       int* __restrict__ fill, int2* __restrict__ edges) {
  int e = blockIdx.x * 256 + threadIdx.x;
  if (e < EE) {
    int s = src[e], d = dst[e];
    int pos = off[d] + atomicAdd(&fill[d], 1);
    edges[pos] = make_int2(s, __float_as_int(dis[s] * dis[d]));
  }
}

// ---- Pass 1: Y[n][t][g] = sum_f X[n][t][f] * W[f][g]  (bf16 out, NODE-MAJOR)
// Per wave: one node's 64x64x64 GEMM via mfma_f32_16x16x32_bf16.
// Operands swapped (A=Wt frag, B=X frag) so D = Y^T tile: lane holds
// t = mt*16 + (lane&15), g = nt*16 + quad*4 + reg. Store target is now the
// node-local 8 KB row Y[n][t][g] -> all of one wave's stores land within
// 8 KB, so L2 write-combines full lines (old [t][N][g] layout scattered
// 32 B chunks across 16 slabs 6.4 MB apart -> HBM write amplification).
__global__ __launch_bounds__(256) void k_gemm(const float* __restrict__ X,
                                              const float* __restrict__ W,
                                              unsigned short* __restrict__ Y) {
  __shared__ unsigned short Wt[64 * 72];  // W transposed [g][f], stride 72 (pad)
  int tid = threadIdx.x;
#pragma unroll
  for (int i = 0; i < 16; ++i) {
    int idx = i * 256 + tid;
    int f = idx >> 6, g = idx & 63;
    Wt[g * 72 + f] = f2bf(W[idx]);
  }
  __syncthreads();
  int wv = tid >> 6;
  int lane = tid & 63;
  int n = blockIdx.x * 4 + wv;
  int m16 = lane & 15, q = lane >> 4;
  const float* Xn = X + (size_t)n * 4096;

  // X fragments (MFMA B-operand): B[k=f][n=t], lane: t=m16, k=kt*32+q*8+j
  bf16x8 afr[4][2];
#pragma unroll
  for (int mt = 0; mt < 4; ++mt)
#pragma unroll
    for (int kt = 0; kt < 2; ++kt) {
      const float* p = Xn + (mt * 16 + m16) * 64 + kt * 32 + q * 8;
      f32x4 lo = *(const f32x4*)p;
      f32x4 hi = *(const f32x4*)(p + 4);
      bf16x8 fr;
      fr[0] = (short)f2bf(lo[0]); fr[1] = (short)f2bf(lo[1]);
      fr[2] = (short)f2bf(lo[2]); fr[3] = (short)f2bf(lo[3]);
      fr[4] = (short)f2bf(hi[0]); fr[5] = (short)f2bf(hi[1]);
      fr[6] = (short)f2bf(hi[2]); fr[7] = (short)f2bf(hi[3]);
      afr[mt][kt] = fr;
    }
  // Wt fragments (MFMA A-operand): A[m=g][k=f], lane: g=nt*16+m16, k=kt*32+q*8+j
  bf16x8 bfr[4][2];
#pragma unroll
  for (int nt = 0; nt < 4; ++nt)
#pragma unroll
    for (int kt = 0; kt < 2; ++kt)
      bfr[nt][kt] = *(const bf16x8*)&Wt[(nt * 16 + m16) * 72 + kt * 32 + q * 8];

  f32x4 acc[4][4];
#pragma unroll
  for (int mt = 0; mt < 4; ++mt)
#pragma unroll
    for (int nt = 0; nt < 4; ++nt)
      acc[mt][nt] = (f32x4){0.f, 0.f, 0.f, 0.f};

#pragma unroll
  for (int kt = 0; kt < 2; ++kt)
#pragma unroll
    for (int mt = 0; mt < 4; ++mt)
#pragma unroll
      for (int nt = 0; nt < 4; ++nt)
        acc[mt][nt] = __builtin_amdgcn_mfma_f32_16x16x32_bf16(
            bfr[nt][kt], afr[mt][kt], acc[mt][nt], 0, 0, 0);

  unsigned short* Yn = Y + (size_t)n * 4096;
#pragma unroll
  for (int mt = 0; mt < 4; ++mt) {
    int t = mt * 16 + m16;
#pragma unroll
    for (int nt = 0; nt < 4; ++nt) {
      int g = nt * 16 + q * 4;
      ushort4 pk;
      pk.x = f2bf(acc[mt][nt][0]);
      pk.y = f2bf(acc[mt][nt][1]);
      pk.z = f2bf(acc[mt][nt][2]);
      pk.w = f2bf(acc[mt][nt][3]);
      *(ushort4*)(Yn + t * 64 + g) = pk;
    }
  }
}

// ---- Pass 2: out[n][t][f] = relu(sum_e w_e * Y[col_e][t][f] + b[f]) ---------
// ONE WAVE PER DST NODE, all 64 timesteps at once:
//  - edge list for node n read ONCE (was 64x, once per t)
//  - per edge, the full 8 KB src row is read as 8 contiguous 1 KB wave-loads
//    (lane covers t = (lane>>3)+8k, f-chunk = (lane&7)*8) -> 8 independent
//    loads in flight per edge + next-edge prefetch hides gather latency
//  - per-lane accumulator acc[8][8] (statically indexed -> registers)
//  - epilogue: bias + relu, 16 KB contiguous fp32 store per node
__global__ __launch_bounds__(256) void k_agg(const unsigned short* __restrict__ Y,
                                             const int2* __restrict__ edges,
                                             const int* __restrict__ off,
                                             const float* __restrict__ bias,
                                             float* __restrict__ out) {
  int wv = threadIdx.x >> 6;
  int lane = threadIdx.x & 63;
  int n = blockIdx.x * 4 + wv;
  int fc = lane & 7;   // feature chunk: f = fc*8 .. fc*8+7
  int tr = lane >> 3;  // t base row:    t = tr + 8k, k = 0..7
  int start = off[n], end = off[n + 1];

  float acc[8][8];
#pragma unroll
  for (int k = 0; k < 8; ++k)
#pragma unroll
    for (int j = 0; j < 8; ++j) acc[k][j] = 0.f;

  int laneoff = tr * 64 + fc * 8;  // element offset within a node row

  int2 e = edges[start];  // start < end always (self edge exists)
  for (int i = start; i < end; ++i) {
    int inext = i + 1;
    int2 en = (inext < end) ? edges[inext] : e;  // prefetch next edge
    float w = __int_as_float(e.y);
    const unsigned short* row = Y + (size_t)e.x * 4096 + laneoff;
#pragma unroll
    for (int k = 0; k < 8; ++k) {
      bf16x8 v = *(const bf16x8*)(row + k * 512);  // t += 8 -> +512 elements
#pragma unroll
      for (int j = 0; j < 8; ++j)
        acc[k][j] += w * bf2f((unsigned short)v[j]);
    }
    e = en;
  }

  float bb[8];
#pragma unroll
  for (int j = 0; j < 8; ++j) bb[j] = bias[fc * 8 + j];

  float* outp = out + (size_t)n * 4096 + laneoff;
#pragma unroll
  for (int k = 0; k < 8; ++k) {
    f32x4 r0, r1;
#pragma unroll
    for (int j = 0; j < 4; ++j) {
      r0[j] = fmaxf(acc[k][j] + bb[j], 0.f);
      r1[j] = fmaxf(acc[k][j + 4] + bb[j + 4], 0.f);
    }
    *(f32x4*)(outp + k * 512) = r0;
    *(f32x4*)(outp + k * 512 + 4) = r1;
  }
}

// ---- launch -----------------------------------------------------------------

extern "C" void kernel_launch(void* const* d_in, const int* in_sizes, int n_in,
                              void* d_out, int out_size, void* d_ws, size_t ws_size,
                              hipStream_t stream) {
  const float* X = (const float*)d_in[0];       // [N,T,F] fp32
  const int* ei = (const int*)d_in[1];          // [2,E] int32: src row0, dst row1
  const float* W = (const float*)d_in[2];       // [F,F]
  const float* b = (const float*)d_in[3];       // [F]
  float* out = (float*)d_out;                   // [N,T,F] fp32

  char* ws = (char*)d_ws;
  // layout: Y (bf16, [N][T][F]) | edges int2 (E+N) | cnt | off | fill | dis
  unsigned short* Y = (unsigned short*)ws;                       // 409,600,000 B
  int2* edges = (int2*)(ws + 409600000ULL);                      //   6,800,000 B
  int* cnt  = (int*)(ws + 416400000ULL);                         //     200,000 B
  int* off  = (int*)(ws + 416600000ULL);                         //     200,004 B
  int* fill = (int*)(ws + 416800008ULL);                         //     200,000 B
  float* dis = (float*)(ws + 417000008ULL);                      //     200,000 B

  hipMemsetAsync(cnt, 0, NN * sizeof(int), stream);

  k_count<<<(EE + 255) / 256, 256, 0, stream>>>(ei + EE, cnt);
  k_dis<<<(NN + 255) / 256, 256, 0, stream>>>(cnt, dis);
  k_scan<<<1, 1024, 0, stream>>>(cnt, off);
  k_self<<<(NN + 255) / 256, 256, 0, stream>>>(off, dis, edges, fill);
  k_fill<<<(EE + 255) / 256, 256, 0, stream>>>(ei, ei + EE, off, dis, fill, edges);
  k_gemm<<<NN / 4, 256, 0, stream>>>(X, W, Y);
  k_agg<<<dim3(NN / 4, 1), 256, 0, stream>>>(Y, edges, off, b, out);
}